// Round 6
// baseline (144.664 us; speedup 1.0000x reference)
//
#include <hip/hip_runtime.h>
#include <hip/hip_bf16.h>

// AdaptiveGraphNetwork via MFMA 16x16x32 bf16. B=4096, N=64, D=32, H=64.
//
// v5: occupancy push done right (v3 failed by VGPR-clamping to 64 -> weight
// spill; v4 win confirmed LDS staging). Changes vs v4:
//  * NBI=1: LDS 75.8KB -> 37.9KB (sH 128x72, sMB 128x40, sX 64x36 f32),
//    below the 3-block (53.3KB) and 4-block (40KB) thresholds.
//  * __launch_bounds__(256,3): min 3 blocks/CU, VGPR cap ~168 -- enough for
//    the 96-VGPR weight fragments + biases (v3's (256,4) forced 64 -> spill).
//  * NBATCH=4 -> grid 1024 WGs (4/CU dispatched) so residency can fill.
//  * T14 async-stage split: next iteration's x prefetched into 8 VGPRs right
//    after the stage barrier; ds_write lands after the end barrier. HBM
//    latency hides under phases A-D.
// Kept from v4: sX staging, swapped A/B/C/D with packed b64 LDS writes and
// full-line global_store_dwordx4; wave-local lgkmcnt fences (A->B, C->D);
// lgkmcnt-only cross-wave barriers.
//
// Fragment maps (m89/m91-verified): A[m=lane&15][k=quad*8+j],
// B[k=quad*8+j][n=lane&15], C/D[row=quad*4+reg][col=lane&15].
// A-frag of W^T == B-frag of W: one fragment set serves both orientations.

typedef __bf16 bf16x8 __attribute__((ext_vector_type(8)));
typedef float  f32x4  __attribute__((ext_vector_type(4)));
typedef unsigned short u16;

#define NBATCH 4          // batches per WG, 1 per iteration
#define ITERS  NBATCH
#define HS  72   // sH row stride in u16 (144 B, 16B-aligned)
#define MBS 40   // sMB row stride in u16 (80 B, 16B-aligned)
#define XS  36   // sX row stride in f32 (144 B, 16B-aligned)

__device__ __forceinline__ u16 f2b(float f) { return __builtin_bit_cast(u16, (__bf16)f); }
__device__ __forceinline__ f32x4 MFMA(bf16x8 a, bf16x8 b, f32x4 c) {
    return __builtin_amdgcn_mfma_f32_16x16x32_bf16(a, b, c, 0, 0, 0);
}
__device__ __forceinline__ bf16x8 pack8(float4 a, float4 b) {
    bf16x8 r = {(__bf16)a.x, (__bf16)a.y, (__bf16)a.z, (__bf16)a.w,
                (__bf16)b.x, (__bf16)b.y, (__bf16)b.z, (__bf16)b.w};
    return r;
}
__device__ __forceinline__ uint2 relu_pack4(f32x4 acc, f32x4 bias) {
    uint2 o;
    o.x = (unsigned)f2b(fmaxf(acc[0] + bias[0], 0.f)) |
          ((unsigned)f2b(fmaxf(acc[1] + bias[1], 0.f)) << 16);
    o.y = (unsigned)f2b(fmaxf(acc[2] + bias[2], 0.f)) |
          ((unsigned)f2b(fmaxf(acc[3] + bias[3], 0.f)) << 16);
    return o;
}
// Wave-local LDS producer->consumer fence (same-wave ds ops are in-order).
__device__ __forceinline__ void wave_lds_fence() {
    asm volatile("s_waitcnt lgkmcnt(0)" ::: "memory");
}
// Cross-wave barrier draining LDS only (no cross-wave global deps).
__device__ __forceinline__ void barrier_lds() {
    asm volatile("s_waitcnt lgkmcnt(0)" ::: "memory");
    __builtin_amdgcn_s_barrier();
    asm volatile("" ::: "memory");
}

__global__ __launch_bounds__(256, 3)
void agn_mfma(const float* __restrict__ x, const float* __restrict__ Wm1,
              const float* __restrict__ bm1, const float* __restrict__ Wm2,
              const float* __restrict__ bm2, const float* __restrict__ Wu1,
              const float* __restrict__ bu1, const float* __restrict__ Wu2,
              const float* __restrict__ bu2, const float* __restrict__ rw_p,
              float* __restrict__ out)
{
    __shared__ __align__(16) u16   sH[128 * HS];   // 18432 B: edge-h rows 0..127; hu rows 0..63
    __shared__ __align__(16) u16   sMB[128 * MBS]; // 10240 B: edge messages
    __shared__ __align__(16) float sX[64 * XS];    //  9216 B: staged x (1 batch)

    const int t = threadIdx.x;
    const int w = t >> 6;
    const int lane = t & 63;
    const int ln = lane & 15;
    const int q  = lane >> 4;

    // ---------------- weight fragments (once per WG) ----------------
    bf16x8 B1a[4], B1b[4], B2[2][2], B3[2][4], B4[2][2];
#pragma unroll
    for (int nt = 0; nt < 4; ++nt)
#pragma unroll
        for (int j = 0; j < 8; ++j) {
            B1a[nt][j] = (__bf16)Wm1[(q * 8 + j) * 64 + nt * 16 + ln];
            B1b[nt][j] = (__bf16)Wm1[(32 + q * 8 + j) * 64 + nt * 16 + ln];
        }
#pragma unroll
    for (int s = 0; s < 2; ++s)
#pragma unroll
        for (int nt = 0; nt < 2; ++nt)
#pragma unroll
            for (int j = 0; j < 8; ++j)
                B2[s][nt][j] = (__bf16)Wm2[(s * 32 + q * 8 + j) * 32 + nt * 16 + ln];
#pragma unroll
    for (int s = 0; s < 2; ++s)
#pragma unroll
        for (int nt = 0; nt < 4; ++nt)
#pragma unroll
            for (int j = 0; j < 8; ++j)
                B3[s][nt][j] = (__bf16)Wu1[(s * 32 + q * 8 + j) * 64 + nt * 16 + ln];
#pragma unroll
    for (int s = 0; s < 2; ++s)
#pragma unroll
        for (int nt = 0; nt < 2; ++nt)
#pragma unroll
            for (int j = 0; j < 8; ++j)
                B4[s][nt][j] = (__bf16)Wu2[(s * 32 + q * 8 + j) * 32 + nt * 16 + ln];

    // Biases. Swapped phases index by C^T row = tile*16 + q*4 + r.
    f32x4 bm1s[4], bu1s[4], bm2s[2], bu2s[2];
#pragma unroll
    for (int ht = 0; ht < 4; ++ht)
#pragma unroll
        for (int r = 0; r < 4; ++r) {
            bm1s[ht][r] = bm1[ht * 16 + q * 4 + r];
            bu1s[ht][r] = bu1[ht * 16 + q * 4 + r];
        }
#pragma unroll
    for (int s = 0; s < 2; ++s)
#pragma unroll
        for (int r = 0; r < 4; ++r) {
            bm2s[s][r] = bm2[s * 16 + q * 4 + r];
            bu2s[s][r] = bu2[s * 16 + q * 4 + r];
        }
    const float rw = rw_p[0];
    const float om = 1.f - rw;

    const size_t base = (size_t)blockIdx.x * (NBATCH * 64 * 32);

    // T14 prefetch: first batch's x slice into registers (32B/thread).
    float4 p0, p1;
    {
        const float* xp = x + base + t * 8;
        p0 = *(const float4*)xp;
        p1 = *(const float4*)(xp + 4);
    }

    for (int it = 0; it < ITERS; ++it) {
        const float* xit = x + base + (size_t)it * (64 * 32);
        float*       oit = out + base + (size_t)it * (64 * 32);

        // ===== Stage: regs -> sX (64 rows x 32 f32, padded stride) =====
        {
            float* dstp = &sX[(t >> 2) * XS + (t & 3) * 8];
            *(float4*)dstp       = p0;
            *(float4*)(dstp + 4) = p1;
        }
        barrier_lds();  // sX ready for all waves

        // T14: issue NEXT iteration's x loads now; vmcnt waited at next stage.
        if (it + 1 < ITERS) {
            const float* xn = xit + 64 * 32 + t * 8;
            p0 = *(const float4*)xn;
            p1 = *(const float4*)(xn + 4);
        }

        // ===== Phase A (swapped): h^T = Wm1t^T@xd^T + Wm1b^T@xs^T, relu =====
#pragma unroll
        for (int m = 0; m < 2; ++m) {
            const int erow = (2 * w + m) * 16 + ln;   // 0..127
            int e = erow;
            if (e >= 126) e = 0;  // pad rows, never read downstream
            const int dst  = (e < 63) ? e : e - 62;
            const int srcn = (e < 63) ? e + 1 : e - 63;
            const float* pd = &sX[dst * XS + q * 8];
            const float* ps = &sX[srcn * XS + q * 8];
            float4 d0 = *(const float4*)pd;
            float4 d1 = *(const float4*)(pd + 4);
            float4 s0 = *(const float4*)ps;
            float4 s1 = *(const float4*)(ps + 4);
            bf16x8 Ad = pack8(d0, d1);
            bf16x8 As = pack8(s0, s1);
            u16* rowp = &sH[erow * HS];
#pragma unroll
            for (int ht = 0; ht < 4; ++ht) {
                f32x4 acc = {0.f, 0.f, 0.f, 0.f};
                acc = MFMA(B1a[ht], Ad, acc);
                acc = MFMA(B1b[ht], As, acc);
                *(uint2*)&rowp[ht * 16 + q * 4] = relu_pack4(acc, bm1s[ht]);
            }
        }
        wave_lds_fence();  // A->B wave-local (rows [32w,32w+32))

        // ===== Phase B (swapped): msgb^T = Wm2^T @ h^T, relu =====
#pragma unroll
        for (int m = 0; m < 2; ++m) {
            const int row = (2 * w + m) * 16 + ln;
            bf16x8 A0 = __builtin_bit_cast(bf16x8, *(const uint4*)&sH[row * HS + q * 8]);
            bf16x8 A1 = __builtin_bit_cast(bf16x8, *(const uint4*)&sH[row * HS + 32 + q * 8]);
#pragma unroll
            for (int s = 0; s < 2; ++s) {
                f32x4 acc = {0.f, 0.f, 0.f, 0.f};
                acc = MFMA(B2[0][s], A0, acc);
                acc = MFMA(B2[1][s], A1, acc);
                *(uint2*)&sMB[row * MBS + s * 16 + q * 4] = relu_pack4(acc, bm2s[s]);
            }
        }
        barrier_lds();  // sMB scatter in C is cross-wave

        // ===== Phase C (swapped): hu^T = Wu1^T @ [x | scatter(msgb)]^T, relu =====
        {
            const int row = w * 16 + ln;   // node 0..63
            const float* p = &sX[row * XS + q * 8];
            float4 a0 = *(const float4*)p;
            float4 a1 = *(const float4*)(p + 4);
            bf16x8 A0 = pack8(a0, a1);
            float mv[8] = {0.f, 0.f, 0.f, 0.f, 0.f, 0.f, 0.f, 0.f};
            if (row < 63) {  // forward edge row -> dst row
                uint4 u = *(const uint4*)&sMB[row * MBS + q * 8];
                const unsigned* pu = (const unsigned*)&u;
#pragma unroll
                for (int h = 0; h < 4; ++h) {
                    mv[2 * h]     += __uint_as_float(pu[h] << 16);
                    mv[2 * h + 1] += __uint_as_float(pu[h] & 0xFFFF0000u);
                }
            }
            if (row > 0) {   // backward edge 62+row -> dst row
                uint4 u = *(const uint4*)&sMB[(62 + row) * MBS + q * 8];
                const unsigned* pu = (const unsigned*)&u;
#pragma unroll
                for (int h = 0; h < 4; ++h) {
                    mv[2 * h]     += __uint_as_float(pu[h] << 16);
                    mv[2 * h + 1] += __uint_as_float(pu[h] & 0xFFFF0000u);
                }
            }
            bf16x8 A1;
#pragma unroll
            for (int j = 0; j < 8; ++j) A1[j] = (__bf16)mv[j];
#pragma unroll
            for (int ht = 0; ht < 4; ++ht) {
                f32x4 acc = {0.f, 0.f, 0.f, 0.f};
                acc = MFMA(B3[0][ht], A0, acc);
                acc = MFMA(B3[1][ht], A1, acc);
                *(uint2*)&sH[row * HS + ht * 16 + q * 4] = relu_pack4(acc, bu1s[ht]);
            }
        }
        wave_lds_fence();  // C->D wave-local (rows [16w,16w+16))

        // ===== Phase D (swapped): out^T = Wu2^T @ hu^T; full-line stores =====
        {
            const int row = w * 16 + ln;   // node 0..63
            bf16x8 A0 = __builtin_bit_cast(bf16x8, *(const uint4*)&sH[row * HS + q * 8]);
            bf16x8 A1 = __builtin_bit_cast(bf16x8, *(const uint4*)&sH[row * HS + 32 + q * 8]);
#pragma unroll
            for (int s = 0; s < 2; ++s) {
                f32x4 acc = {0.f, 0.f, 0.f, 0.f};
                acc = MFMA(B4[0][s], A0, acc);
                acc = MFMA(B4[1][s], A1, acc);
                f32x4 xv = *(const f32x4*)&sX[row * XS + s * 16 + q * 4];
                float4 o;
                o.x = rw * (acc[0] + bu2s[s][0]) + om * xv[0];
                o.y = rw * (acc[1] + bu2s[s][1]) + om * xv[1];
                o.z = rw * (acc[2] + bu2s[s][2]) + om * xv[2];
                o.w = rw * (acc[3] + bu2s[s][3]) + om * xv[3];
                *(float4*)(oit + row * 32 + s * 16 + q * 4) = o;
            }
        }
        barrier_lds();  // sH/sMB/sX consumed before next iter overwrites
    }
}

extern "C" void kernel_launch(void* const* d_in, const int* in_sizes, int n_in,
                              void* d_out, int out_size, void* d_ws, size_t ws_size,
                              hipStream_t stream) {
    const float* x   = (const float*)d_in[0];
    const float* Wm1 = (const float*)d_in[1];
    const float* bm1 = (const float*)d_in[2];
    const float* Wm2 = (const float*)d_in[3];
    const float* bm2 = (const float*)d_in[4];
    const float* Wu1 = (const float*)d_in[5];
    const float* bu1 = (const float*)d_in[6];
    const float* Wu2 = (const float*)d_in[7];
    const float* bu2 = (const float*)d_in[8];
    const float* rw  = (const float*)d_in[9];
    float* out = (float*)d_out;

    const int B = in_sizes[0] / (64 * 32);
    agn_mfma<<<B / NBATCH, 256, 0, stream>>>(x, Wm1, bm1, Wm2, bm2, Wu1, bu1, Wu2, bu2, rw, out);
}

// Round 7
// 118.703 us; speedup vs baseline: 1.2187x; 1.2187x over previous
//
#include <hip/hip_runtime.h>
#include <hip/hip_bf16.h>

// AdaptiveGraphNetwork via MFMA 16x16x32 bf16. B=4096, N=64, D=32, H=64.
//
// v6: break the VGPR/occupancy deadlock. v3/v5 proved launch_bounds-clamping
// spills the ~140-VGPR weight+bias register set (v5: VGPR 84, WRITE 2x ideal,
// 60us). v6 reduces DEMAND instead: B2/B3/B4 fragments (16 x 1KB) + biases
// live in LDS in exact per-lane fragment layout (ds_read_b128 returns the
// identical register image); only hot B1a/B1b stay in registers (32 VGPRs).
// x is staged as bf16 (sXb, 5.1KB) so A/C read bf16x8 frags directly (no
// pack8 cvt chains). LDS = 50,944B < 53,333 -> 3 blocks/CU = 12 waves/CU
// (1.5x v4) with __launch_bounds__(256,2) (v2/v4-proven: no spill).
// NBATCH=2, grid 2048.
//
// Kept: swapped A/B/C/D MFMA (packed b64 LDS writes, full-line stores),
// wave-local lgkmcnt fences (A->B, C->D), lgkmcnt-only cross-wave barriers.
//
// Fragment maps (m89/m91-verified): A[m=lane&15][k=quad*8+j],
// B[k=quad*8+j][n=lane&15], C/D[row=quad*4+reg][col=lane&15].
// A-frag of W^T == B-frag of W: one fragment image serves both orientations.

typedef __bf16 bf16x8 __attribute__((ext_vector_type(8)));
typedef float  f32x4  __attribute__((ext_vector_type(4)));
typedef unsigned short u16;

#define NBATCH 2
#define ITERS  NBATCH
#define HS  72   // sH row stride in u16 (144 B)
#define MBS 40   // sMB row stride in u16 (80 B)
#define XBS 40   // sXb row stride in u16 (80 B)

// u16 offsets into the single smem block (all 16B-aligned)
#define SH_OFF   0                     // 128*72  = 9216 u16
#define SMB_OFF  (SH_OFF + 128 * HS)   // 9216
#define SXB_OFF  (SMB_OFF + 128 * MBS) // 14336
#define FB2_OFF  (SXB_OFF + 64 * XBS)  // 16896 : 4 frags * 512 u16
#define FB3_OFF  (FB2_OFF + 4 * 512)   // 18944 : 8 frags
#define FB4_OFF  (FB3_OFF + 8 * 512)   // 23040 : 4 frags
#define BIAS_OFF (FB4_OFF + 4 * 512)   // 25088 : 192 f32 = 384 u16
#define SMEM_U16 (BIAS_OFF + 384)      // 25472 u16 = 50944 B

__device__ __forceinline__ u16 f2b(float f) { return __builtin_bit_cast(u16, (__bf16)f); }
__device__ __forceinline__ f32x4 MFMA(bf16x8 a, bf16x8 b, f32x4 c) {
    return __builtin_amdgcn_mfma_f32_16x16x32_bf16(a, b, c, 0, 0, 0);
}
__device__ __forceinline__ bf16x8 pack8(float4 a, float4 b) {
    bf16x8 r = {(__bf16)a.x, (__bf16)a.y, (__bf16)a.z, (__bf16)a.w,
                (__bf16)b.x, (__bf16)b.y, (__bf16)b.z, (__bf16)b.w};
    return r;
}
__device__ __forceinline__ uint2 relu_pack4(f32x4 acc, f32x4 bias) {
    uint2 o;
    o.x = (unsigned)f2b(fmaxf(acc[0] + bias[0], 0.f)) |
          ((unsigned)f2b(fmaxf(acc[1] + bias[1], 0.f)) << 16);
    o.y = (unsigned)f2b(fmaxf(acc[2] + bias[2], 0.f)) |
          ((unsigned)f2b(fmaxf(acc[3] + bias[3], 0.f)) << 16);
    return o;
}
// Wave-local LDS producer->consumer fence (same-wave ds ops are in-order).
__device__ __forceinline__ void wave_lds_fence() {
    asm volatile("s_waitcnt lgkmcnt(0)" ::: "memory");
}
// Cross-wave barrier draining LDS only (no cross-wave global deps).
__device__ __forceinline__ void barrier_lds() {
    asm volatile("s_waitcnt lgkmcnt(0)" ::: "memory");
    __builtin_amdgcn_s_barrier();
    asm volatile("" ::: "memory");
}

__global__ __launch_bounds__(256, 2)
void agn_mfma(const float* __restrict__ x, const float* __restrict__ Wm1,
              const float* __restrict__ bm1, const float* __restrict__ Wm2,
              const float* __restrict__ bm2, const float* __restrict__ Wu1,
              const float* __restrict__ bu1, const float* __restrict__ Wu2,
              const float* __restrict__ bu2, const float* __restrict__ rw_p,
              float* __restrict__ out)
{
    __shared__ __align__(16) u16 smem[SMEM_U16];  // 50944 B -> 3 blocks/CU

    const int t = threadIdx.x;
    const int w = t >> 6;
    const int lane = t & 63;
    const int ln = lane & 15;
    const int q  = lane >> 4;

    float* biasL = (float*)&smem[BIAS_OFF];  // [0..63]=bm1, [64..127]=bu1,
                                             // [128..159]=bm2, [160..191]=bu2

    // ---------------- init: biases + cold weight frags -> LDS ----------------
    if (t < 64)  { biasL[t] = bm1[t]; biasL[64 + t] = bu1[t]; }
    if (t < 32)  { biasL[128 + t] = bm2[t]; biasL[160 + t] = bu2[t]; }
    if (w == 0) {
        // B2 frags: f = ks*2 + ot
#pragma unroll
        for (int ks = 0; ks < 2; ++ks)
#pragma unroll
            for (int ot = 0; ot < 2; ++ot) {
                bf16x8 v;
#pragma unroll
                for (int j = 0; j < 8; ++j)
                    v[j] = (__bf16)Wm2[(ks * 32 + q * 8 + j) * 32 + ot * 16 + ln];
                *(uint4*)&smem[FB2_OFF + (ks * 2 + ot) * 512 + lane * 8] =
                    __builtin_bit_cast(uint4, v);
            }
        // B3 frags: f = ks*4 + ht
#pragma unroll
        for (int ks = 0; ks < 2; ++ks)
#pragma unroll
            for (int ht = 0; ht < 4; ++ht) {
                bf16x8 v;
#pragma unroll
                for (int j = 0; j < 8; ++j)
                    v[j] = (__bf16)Wu1[(ks * 32 + q * 8 + j) * 64 + ht * 16 + ln];
                *(uint4*)&smem[FB3_OFF + (ks * 4 + ht) * 512 + lane * 8] =
                    __builtin_bit_cast(uint4, v);
            }
        // B4 frags: f = ks*2 + s
#pragma unroll
        for (int ks = 0; ks < 2; ++ks)
#pragma unroll
            for (int s = 0; s < 2; ++s) {
                bf16x8 v;
#pragma unroll
                for (int j = 0; j < 8; ++j)
                    v[j] = (__bf16)Wu2[(ks * 32 + q * 8 + j) * 32 + s * 16 + ln];
                *(uint4*)&smem[FB4_OFF + (ks * 2 + s) * 512 + lane * 8] =
                    __builtin_bit_cast(uint4, v);
            }
    }

    // Hot B1 fragments stay in registers (used 2x per A-phase MFMA).
    bf16x8 B1a[4], B1b[4];
#pragma unroll
    for (int nt = 0; nt < 4; ++nt)
#pragma unroll
        for (int j = 0; j < 8; ++j) {
            B1a[nt][j] = (__bf16)Wm1[(q * 8 + j) * 64 + nt * 16 + ln];
            B1b[nt][j] = (__bf16)Wm1[(32 + q * 8 + j) * 64 + nt * 16 + ln];
        }

    const float rw = rw_p[0];
    const float om = 1.f - rw;
    const size_t base = (size_t)blockIdx.x * (NBATCH * 64 * 32);

    for (int it = 0; it < ITERS; ++it) {
        const float* xit = x + base + (size_t)it * (64 * 32);
        float*       oit = out + base + (size_t)it * (64 * 32);

        // ===== Stage: x (64x32 f32) -> sXb bf16, coalesced 32B/thread =====
        {
            const int row = t >> 2, ch = t & 3;
            const float* src = xit + row * 32 + ch * 8;
            float4 v0 = *(const float4*)src;
            float4 v1 = *(const float4*)(src + 4);
            *(uint4*)&smem[SXB_OFF + row * XBS + ch * 8] =
                __builtin_bit_cast(uint4, pack8(v0, v1));
        }
        barrier_lds();  // also covers init visibility on iter 0

        // ===== Phase A (swapped): h^T = Wm1t^T@xd^T + Wm1b^T@xs^T, relu =====
#pragma unroll
        for (int m = 0; m < 2; ++m) {
            const int erow = (2 * w + m) * 16 + ln;   // 0..127
            int e = erow;
            if (e >= 126) e = 0;  // pad rows, never read downstream
            const int dst  = (e < 63) ? e : e - 62;
            const int srcn = (e < 63) ? e + 1 : e - 63;
            bf16x8 Ad = __builtin_bit_cast(bf16x8, *(const uint4*)&smem[SXB_OFF + dst * XBS + q * 8]);
            bf16x8 As = __builtin_bit_cast(bf16x8, *(const uint4*)&smem[SXB_OFF + srcn * XBS + q * 8]);
            u16* rowp = &smem[SH_OFF + erow * HS];
#pragma unroll
            for (int ht = 0; ht < 4; ++ht) {
                f32x4 bias = *(const f32x4*)&biasL[ht * 16 + q * 4];
                f32x4 acc = {0.f, 0.f, 0.f, 0.f};
                acc = MFMA(B1a[ht], Ad, acc);
                acc = MFMA(B1b[ht], As, acc);
                *(uint2*)&rowp[ht * 16 + q * 4] = relu_pack4(acc, bias);
            }
        }
        wave_lds_fence();  // A->B wave-local (rows [32w,32w+32))

        // ===== Phase B (swapped): msgb^T = Wm2^T @ h^T, relu =====
#pragma unroll
        for (int m = 0; m < 2; ++m) {
            const int row = (2 * w + m) * 16 + ln;
            bf16x8 A0 = __builtin_bit_cast(bf16x8, *(const uint4*)&smem[SH_OFF + row * HS + q * 8]);
            bf16x8 A1 = __builtin_bit_cast(bf16x8, *(const uint4*)&smem[SH_OFF + row * HS + 32 + q * 8]);
#pragma unroll
            for (int s = 0; s < 2; ++s) {
                bf16x8 W0 = __builtin_bit_cast(bf16x8, *(const uint4*)&smem[FB2_OFF + (0 * 2 + s) * 512 + lane * 8]);
                bf16x8 W1 = __builtin_bit_cast(bf16x8, *(const uint4*)&smem[FB2_OFF + (1 * 2 + s) * 512 + lane * 8]);
                f32x4 bias = *(const f32x4*)&biasL[128 + s * 16 + q * 4];
                f32x4 acc = {0.f, 0.f, 0.f, 0.f};
                acc = MFMA(W0, A0, acc);
                acc = MFMA(W1, A1, acc);
                *(uint2*)&smem[SMB_OFF + row * MBS + s * 16 + q * 4] = relu_pack4(acc, bias);
            }
        }
        barrier_lds();  // sMB scatter in C is cross-wave

        // ===== Phase C (swapped): hu^T = Wu1^T @ [x | scatter(msgb)]^T, relu =====
        {
            const int row = w * 16 + ln;   // node 0..63
            bf16x8 A0 = __builtin_bit_cast(bf16x8, *(const uint4*)&smem[SXB_OFF + row * XBS + q * 8]);
            float mv[8] = {0.f, 0.f, 0.f, 0.f, 0.f, 0.f, 0.f, 0.f};
            if (row < 63) {  // forward edge row -> dst row
                uint4 u = *(const uint4*)&smem[SMB_OFF + row * MBS + q * 8];
                const unsigned* pu = (const unsigned*)&u;
#pragma unroll
                for (int h = 0; h < 4; ++h) {
                    mv[2 * h]     += __uint_as_float(pu[h] << 16);
                    mv[2 * h + 1] += __uint_as_float(pu[h] & 0xFFFF0000u);
                }
            }
            if (row > 0) {   // backward edge 62+row -> dst row
                uint4 u = *(const uint4*)&smem[SMB_OFF + (62 + row) * MBS + q * 8];
                const unsigned* pu = (const unsigned*)&u;
#pragma unroll
                for (int h = 0; h < 4; ++h) {
                    mv[2 * h]     += __uint_as_float(pu[h] << 16);
                    mv[2 * h + 1] += __uint_as_float(pu[h] & 0xFFFF0000u);
                }
            }
            bf16x8 A1;
#pragma unroll
            for (int j = 0; j < 8; ++j) A1[j] = (__bf16)mv[j];
#pragma unroll
            for (int ht = 0; ht < 4; ++ht) {
                bf16x8 W0 = __builtin_bit_cast(bf16x8, *(const uint4*)&smem[FB3_OFF + (0 * 4 + ht) * 512 + lane * 8]);
                bf16x8 W1 = __builtin_bit_cast(bf16x8, *(const uint4*)&smem[FB3_OFF + (1 * 4 + ht) * 512 + lane * 8]);
                f32x4 bias = *(const f32x4*)&biasL[64 + ht * 16 + q * 4];
                f32x4 acc = {0.f, 0.f, 0.f, 0.f};
                acc = MFMA(W0, A0, acc);
                acc = MFMA(W1, A1, acc);
                *(uint2*)&smem[SH_OFF + row * HS + ht * 16 + q * 4] = relu_pack4(acc, bias);
            }
        }
        wave_lds_fence();  // C->D wave-local (rows [16w,16w+16))

        // ===== Phase D (swapped): out^T = Wu2^T @ hu^T; full-line stores =====
        {
            const int row = w * 16 + ln;   // node 0..63
            bf16x8 A0 = __builtin_bit_cast(bf16x8, *(const uint4*)&smem[SH_OFF + row * HS + q * 8]);
            bf16x8 A1 = __builtin_bit_cast(bf16x8, *(const uint4*)&smem[SH_OFF + row * HS + 32 + q * 8]);
#pragma unroll
            for (int s = 0; s < 2; ++s) {
                bf16x8 W0 = __builtin_bit_cast(bf16x8, *(const uint4*)&smem[FB4_OFF + (0 * 2 + s) * 512 + lane * 8]);
                bf16x8 W1 = __builtin_bit_cast(bf16x8, *(const uint4*)&smem[FB4_OFF + (1 * 2 + s) * 512 + lane * 8]);
                f32x4 bias = *(const f32x4*)&biasL[160 + s * 16 + q * 4];
                f32x4 acc = {0.f, 0.f, 0.f, 0.f};
                acc = MFMA(W0, A0, acc);
                acc = MFMA(W1, A1, acc);
                float4 xv = *(const float4*)(xit + row * 32 + s * 16 + q * 4);  // f32 residual
                float4 o;
                o.x = rw * (acc[0] + bias[0]) + om * xv.x;
                o.y = rw * (acc[1] + bias[1]) + om * xv.y;
                o.z = rw * (acc[2] + bias[2]) + om * xv.z;
                o.w = rw * (acc[3] + bias[3]) + om * xv.w;
                *(float4*)(oit + row * 32 + s * 16 + q * 4) = o;
            }
        }
        barrier_lds();  // sH/sMB/sXb consumed before next iter overwrites
    }
}

extern "C" void kernel_launch(void* const* d_in, const int* in_sizes, int n_in,
                              void* d_out, int out_size, void* d_ws, size_t ws_size,
                              hipStream_t stream) {
    const float* x   = (const float*)d_in[0];
    const float* Wm1 = (const float*)d_in[1];
    const float* bm1 = (const float*)d_in[2];
    const float* Wm2 = (const float*)d_in[3];
    const float* bm2 = (const float*)d_in[4];
    const float* Wu1 = (const float*)d_in[5];
    const float* bu1 = (const float*)d_in[6];
    const float* Wu2 = (const float*)d_in[7];
    const float* bu2 = (const float*)d_in[8];
    const float* rw  = (const float*)d_in[9];
    float* out = (float*)d_out;

    const int B = in_sizes[0] / (64 * 32);
    agn_mfma<<<B / NBATCH, 256, 0, stream>>>(x, Wm1, bm1, Wm2, bm2, Wu1, bu1, Wu2, bu2, rw, out);
}

// Round 8
// 114.931 us; speedup vs baseline: 1.2587x; 1.0328x over previous
//
#include <hip/hip_runtime.h>
#include <hip/hip_bf16.h>

// AdaptiveGraphNetwork via MFMA 16x16x32 bf16. B=4096, N=64, D=32, H=64.
//
// v7 = v6 skeleton (weights B2-B4 + biases in LDS fragment-image layout,
// bf16 x staging, NBI=1, 50.9KB LDS -> 3 blocks/CU, LB(256,2)) + additive
// latency cuts. v4/v6 pair showed +50% occupancy bought nothing: the bound
// is per-block serial latency. Changes:
//  * NBATCH 2->4 (grid 1024 >= 768 resident): half the prologues/launch.
//  * Prologue weight-frag loads spread across all 4 waves (was w==0 only).
//  * T14 prefetch restored (v5-proven): next batch's x loaded into regs
//    right after stage barrier; ds_write at loop top. Stage HBM latency
//    hides under phases A-D of the previous batch.
//  * Phase-B W-frag + bias LDS reads hoisted out of the m-loop (s-only).
//  * Phase-D residual x loads issued right after the B-barrier (L2 latency
//    hides under phase C).
//
// Fragment maps (m89/m91-verified): A[m=lane&15][k=quad*8+j],
// B[k=quad*8+j][n=lane&15], C/D[row=quad*4+reg][col=lane&15].
// A-frag of W^T == B-frag of W: one fragment image serves both orientations.

typedef __bf16 bf16x8 __attribute__((ext_vector_type(8)));
typedef float  f32x4  __attribute__((ext_vector_type(4)));
typedef unsigned short u16;

#define NBATCH 4
#define ITERS  NBATCH
#define HS  72   // sH row stride in u16 (144 B)
#define MBS 40   // sMB row stride in u16 (80 B)
#define XBS 40   // sXb row stride in u16 (80 B)

// u16 offsets into the single smem block (all 16B-aligned)
#define SH_OFF   0                     // 128*72  = 9216 u16
#define SMB_OFF  (SH_OFF + 128 * HS)   // 9216
#define SXB_OFF  (SMB_OFF + 128 * MBS) // 14336
#define FB2_OFF  (SXB_OFF + 64 * XBS)  // 16896 : 4 frags * 512 u16
#define FB3_OFF  (FB2_OFF + 4 * 512)   // 18944 : 8 frags
#define FB4_OFF  (FB3_OFF + 8 * 512)   // 23040 : 4 frags
#define BIAS_OFF (FB4_OFF + 4 * 512)   // 25088 : 192 f32 = 384 u16
#define SMEM_U16 (BIAS_OFF + 384)      // 25472 u16 = 50944 B

__device__ __forceinline__ u16 f2b(float f) { return __builtin_bit_cast(u16, (__bf16)f); }
__device__ __forceinline__ f32x4 MFMA(bf16x8 a, bf16x8 b, f32x4 c) {
    return __builtin_amdgcn_mfma_f32_16x16x32_bf16(a, b, c, 0, 0, 0);
}
__device__ __forceinline__ bf16x8 pack8(float4 a, float4 b) {
    bf16x8 r = {(__bf16)a.x, (__bf16)a.y, (__bf16)a.z, (__bf16)a.w,
                (__bf16)b.x, (__bf16)b.y, (__bf16)b.z, (__bf16)b.w};
    return r;
}
__device__ __forceinline__ uint2 relu_pack4(f32x4 acc, f32x4 bias) {
    uint2 o;
    o.x = (unsigned)f2b(fmaxf(acc[0] + bias[0], 0.f)) |
          ((unsigned)f2b(fmaxf(acc[1] + bias[1], 0.f)) << 16);
    o.y = (unsigned)f2b(fmaxf(acc[2] + bias[2], 0.f)) |
          ((unsigned)f2b(fmaxf(acc[3] + bias[3], 0.f)) << 16);
    return o;
}
// Wave-local LDS producer->consumer fence (same-wave ds ops are in-order).
__device__ __forceinline__ void wave_lds_fence() {
    asm volatile("s_waitcnt lgkmcnt(0)" ::: "memory");
}
// Cross-wave barrier draining LDS only (no cross-wave global deps).
__device__ __forceinline__ void barrier_lds() {
    asm volatile("s_waitcnt lgkmcnt(0)" ::: "memory");
    __builtin_amdgcn_s_barrier();
    asm volatile("" ::: "memory");
}

__global__ __launch_bounds__(256, 2)
void agn_mfma(const float* __restrict__ x, const float* __restrict__ Wm1,
              const float* __restrict__ bm1, const float* __restrict__ Wm2,
              const float* __restrict__ bm2, const float* __restrict__ Wu1,
              const float* __restrict__ bu1, const float* __restrict__ Wu2,
              const float* __restrict__ bu2, const float* __restrict__ rw_p,
              float* __restrict__ out)
{
    __shared__ __align__(16) u16 smem[SMEM_U16];  // 50944 B -> 3 blocks/CU

    const int t = threadIdx.x;
    const int w = t >> 6;
    const int lane = t & 63;
    const int ln = lane & 15;
    const int q  = lane >> 4;

    float* biasL = (float*)&smem[BIAS_OFF];  // [0..63]=bm1, [64..127]=bu1,
                                             // [128..159]=bm2, [160..191]=bu2

    // ---------------- prologue: biases + cold frags -> LDS (all waves) -----
    if (t < 64)  { biasL[t] = bm1[t]; biasL[64 + t] = bu1[t]; }
    if (t < 32)  { biasL[128 + t] = bm2[t]; biasL[160 + t] = bu2[t]; }
    if (w == 0) {                       // B2 frags: f = ks*2 + ot
#pragma unroll
        for (int ks = 0; ks < 2; ++ks)
#pragma unroll
            for (int ot = 0; ot < 2; ++ot) {
                bf16x8 v;
#pragma unroll
                for (int j = 0; j < 8; ++j)
                    v[j] = (__bf16)Wm2[(ks * 32 + q * 8 + j) * 32 + ot * 16 + ln];
                *(uint4*)&smem[FB2_OFF + (ks * 2 + ot) * 512 + lane * 8] =
                    __builtin_bit_cast(uint4, v);
            }
    } else if (w == 1 || w == 2) {      // B3 frags: f = ks*4 + ht, ks = w-1
        const int ks = w - 1;
#pragma unroll
        for (int ht = 0; ht < 4; ++ht) {
            bf16x8 v;
#pragma unroll
            for (int j = 0; j < 8; ++j)
                v[j] = (__bf16)Wu1[(ks * 32 + q * 8 + j) * 64 + ht * 16 + ln];
            *(uint4*)&smem[FB3_OFF + (ks * 4 + ht) * 512 + lane * 8] =
                __builtin_bit_cast(uint4, v);
        }
    } else {                            // B4 frags: f = ks*2 + s
#pragma unroll
        for (int ks = 0; ks < 2; ++ks)
#pragma unroll
            for (int s = 0; s < 2; ++s) {
                bf16x8 v;
#pragma unroll
                for (int j = 0; j < 8; ++j)
                    v[j] = (__bf16)Wu2[(ks * 32 + q * 8 + j) * 32 + s * 16 + ln];
                *(uint4*)&smem[FB4_OFF + (ks * 2 + s) * 512 + lane * 8] =
                    __builtin_bit_cast(uint4, v);
            }
    }

    // Hot B1 fragments in registers (used 2x per A-phase MFMA).
    bf16x8 B1a[4], B1b[4];
#pragma unroll
    for (int nt = 0; nt < 4; ++nt)
#pragma unroll
        for (int j = 0; j < 8; ++j) {
            B1a[nt][j] = (__bf16)Wm1[(q * 8 + j) * 64 + nt * 16 + ln];
            B1b[nt][j] = (__bf16)Wm1[(32 + q * 8 + j) * 64 + nt * 16 + ln];
        }

    const float rw = rw_p[0];
    const float om = 1.f - rw;
    const size_t base = (size_t)blockIdx.x * (NBATCH * 64 * 32);

    // T14: first batch's x slice into registers (32B/thread, coalesced).
    float4 p0, p1;
    {
        const float* xp = x + base + t * 8;
        p0 = *(const float4*)xp;
        p1 = *(const float4*)(xp + 4);
    }

    for (int it = 0; it < ITERS; ++it) {
        const float* xit = x + base + (size_t)it * (64 * 32);
        float*       oit = out + base + (size_t)it * (64 * 32);

        // ===== Stage: regs -> sXb bf16 (row = t>>2, chunk = t&3) =====
        *(uint4*)&smem[SXB_OFF + (t >> 2) * XBS + (t & 3) * 8] =
            __builtin_bit_cast(uint4, pack8(p0, p1));
        barrier_lds();  // sXb ready (also covers prologue on iter 0)

        // T14: issue NEXT batch's x loads now; latency hides under A-D.
        if (it + 1 < ITERS) {
            const float* xn = xit + 64 * 32 + t * 8;
            p0 = *(const float4*)xn;
            p1 = *(const float4*)(xn + 4);
        }

        // ===== Phase A (swapped): h^T = Wm1t^T@xd^T + Wm1b^T@xs^T, relu =====
#pragma unroll
        for (int m = 0; m < 2; ++m) {
            const int erow = (2 * w + m) * 16 + ln;   // 0..127
            int e = erow;
            if (e >= 126) e = 0;  // pad rows, never read downstream
            const int dst  = (e < 63) ? e : e - 62;
            const int srcn = (e < 63) ? e + 1 : e - 63;
            bf16x8 Ad = __builtin_bit_cast(bf16x8, *(const uint4*)&smem[SXB_OFF + dst * XBS + q * 8]);
            bf16x8 As = __builtin_bit_cast(bf16x8, *(const uint4*)&smem[SXB_OFF + srcn * XBS + q * 8]);
            u16* rowp = &smem[SH_OFF + erow * HS];
#pragma unroll
            for (int ht = 0; ht < 4; ++ht) {
                f32x4 bias = *(const f32x4*)&biasL[ht * 16 + q * 4];
                f32x4 acc = {0.f, 0.f, 0.f, 0.f};
                acc = MFMA(B1a[ht], Ad, acc);
                acc = MFMA(B1b[ht], As, acc);
                *(uint2*)&rowp[ht * 16 + q * 4] = relu_pack4(acc, bias);
            }
        }
        wave_lds_fence();  // A->B wave-local (rows [32w,32w+32))

        // ===== Phase B (swapped): msgb^T = Wm2^T @ h^T, relu =====
        {
            bf16x8 W2[2][2];
            f32x4 bb[2];
#pragma unroll
            for (int s = 0; s < 2; ++s) {
                W2[0][s] = __builtin_bit_cast(bf16x8, *(const uint4*)&smem[FB2_OFF + (0 * 2 + s) * 512 + lane * 8]);
                W2[1][s] = __builtin_bit_cast(bf16x8, *(const uint4*)&smem[FB2_OFF + (1 * 2 + s) * 512 + lane * 8]);
                bb[s] = *(const f32x4*)&biasL[128 + s * 16 + q * 4];
            }
#pragma unroll
            for (int m = 0; m < 2; ++m) {
                const int row = (2 * w + m) * 16 + ln;
                bf16x8 A0 = __builtin_bit_cast(bf16x8, *(const uint4*)&smem[SH_OFF + row * HS + q * 8]);
                bf16x8 A1 = __builtin_bit_cast(bf16x8, *(const uint4*)&smem[SH_OFF + row * HS + 32 + q * 8]);
#pragma unroll
                for (int s = 0; s < 2; ++s) {
                    f32x4 acc = {0.f, 0.f, 0.f, 0.f};
                    acc = MFMA(W2[0][s], A0, acc);
                    acc = MFMA(W2[1][s], A1, acc);
                    *(uint2*)&smem[SMB_OFF + row * MBS + s * 16 + q * 4] = relu_pack4(acc, bb[s]);
                }
            }
        }
        barrier_lds();  // sMB scatter in C is cross-wave

        // Early residual loads for phase D (L2-warm; latency hides under C).
        const int drow = w * 16 + ln;   // node 0..63 (same row C uses)
        float4 xv0 = *(const float4*)(xit + drow * 32 + 0 * 16 + q * 4);
        float4 xv1 = *(const float4*)(xit + drow * 32 + 1 * 16 + q * 4);

        // ===== Phase C (swapped): hu^T = Wu1^T @ [x | scatter(msgb)]^T, relu =====
        {
            const int row = drow;
            bf16x8 A0 = __builtin_bit_cast(bf16x8, *(const uint4*)&smem[SXB_OFF + row * XBS + q * 8]);
            float mv[8] = {0.f, 0.f, 0.f, 0.f, 0.f, 0.f, 0.f, 0.f};
            if (row < 63) {  // forward edge row -> dst row
                uint4 u = *(const uint4*)&smem[SMB_OFF + row * MBS + q * 8];
                const unsigned* pu = (const unsigned*)&u;
#pragma unroll
                for (int h = 0; h < 4; ++h) {
                    mv[2 * h]     += __uint_as_float(pu[h] << 16);
                    mv[2 * h + 1] += __uint_as_float(pu[h] & 0xFFFF0000u);
                }
            }
            if (row > 0) {   // backward edge 62+row -> dst row
                uint4 u = *(const uint4*)&smem[SMB_OFF + (62 + row) * MBS + q * 8];
                const unsigned* pu = (const unsigned*)&u;
#pragma unroll
                for (int h = 0; h < 4; ++h) {
                    mv[2 * h]     += __uint_as_float(pu[h] << 16);
                    mv[2 * h + 1] += __uint_as_float(pu[h] & 0xFFFF0000u);
                }
            }
            bf16x8 A1;
#pragma unroll
            for (int j = 0; j < 8; ++j) A1[j] = (__bf16)mv[j];
#pragma unroll
            for (int ht = 0; ht < 4; ++ht) {
                bf16x8 W0 = __builtin_bit_cast(bf16x8, *(const uint4*)&smem[FB3_OFF + (0 * 4 + ht) * 512 + lane * 8]);
                bf16x8 W1 = __builtin_bit_cast(bf16x8, *(const uint4*)&smem[FB3_OFF + (1 * 4 + ht) * 512 + lane * 8]);
                f32x4 bias = *(const f32x4*)&biasL[64 + ht * 16 + q * 4];
                f32x4 acc = {0.f, 0.f, 0.f, 0.f};
                acc = MFMA(W0, A0, acc);
                acc = MFMA(W1, A1, acc);
                *(uint2*)&smem[SH_OFF + row * HS + ht * 16 + q * 4] = relu_pack4(acc, bias);
            }
        }
        wave_lds_fence();  // C->D wave-local (rows [16w,16w+16))

        // ===== Phase D (swapped): out^T = Wu2^T @ hu^T; full-line stores =====
        {
            const int row = drow;
            bf16x8 A0 = __builtin_bit_cast(bf16x8, *(const uint4*)&smem[SH_OFF + row * HS + q * 8]);
            bf16x8 A1 = __builtin_bit_cast(bf16x8, *(const uint4*)&smem[SH_OFF + row * HS + 32 + q * 8]);
#pragma unroll
            for (int s = 0; s < 2; ++s) {
                bf16x8 W0 = __builtin_bit_cast(bf16x8, *(const uint4*)&smem[FB4_OFF + (0 * 2 + s) * 512 + lane * 8]);
                bf16x8 W1 = __builtin_bit_cast(bf16x8, *(const uint4*)&smem[FB4_OFF + (1 * 2 + s) * 512 + lane * 8]);
                f32x4 bias = *(const f32x4*)&biasL[160 + s * 16 + q * 4];
                f32x4 acc = {0.f, 0.f, 0.f, 0.f};
                acc = MFMA(W0, A0, acc);
                acc = MFMA(W1, A1, acc);
                const float4 xv = s ? xv1 : xv0;
                float4 o;
                o.x = rw * (acc[0] + bias[0]) + om * xv.x;
                o.y = rw * (acc[1] + bias[1]) + om * xv.y;
                o.z = rw * (acc[2] + bias[2]) + om * xv.z;
                o.w = rw * (acc[3] + bias[3]) + om * xv.w;
                *(float4*)(oit + row * 32 + s * 16 + q * 4) = o;
            }
        }
        barrier_lds();  // sH/sMB/sXb consumed before next iter overwrites
    }
}

extern "C" void kernel_launch(void* const* d_in, const int* in_sizes, int n_in,
                              void* d_out, int out_size, void* d_ws, size_t ws_size,
                              hipStream_t stream) {
    const float* x   = (const float*)d_in[0];
    const float* Wm1 = (const float*)d_in[1];
    const float* bm1 = (const float*)d_in[2];
    const float* Wm2 = (const float*)d_in[3];
    const float* bm2 = (const float*)d_in[4];
    const float* Wu1 = (const float*)d_in[5];
    const float* bu1 = (const float*)d_in[6];
    const float* Wu2 = (const float*)d_in[7];
    const float* bu2 = (const float*)d_in[8];
    const float* rw  = (const float*)d_in[9];
    float* out = (float*)d_out;

    const int B = in_sizes[0] / (64 * 32);
    agn_mfma<<<B / NBATCH, 256, 0, stream>>>(x, Wm1, bm1, Wm2, bm2, Wu1, bu1, Wu2, bu2, rw, out);
}